// Round 1
// baseline (838.278 us; speedup 1.0000x reference)
//
#include <hip/hip_runtime.h>
#include <cstdint>
#include <cmath>

#define BATCH 16
#define CH    96
#define HW    50176      // 224*224
#define KSEL  25088      // int(0.5 * HW)
#define HW4   (HW/4)     // 12544

// ---------------- workspace layout (all within d_ws) ----------------
// [0]                      uint32 ebits   [BATCH*HW]      3,211,264 B
// [+B*HW]                  uint32 hist_hi [BATCH*65536]   4,194,304 B
// [+B*65536]               uint32 hist_lo [BATCH*65536]   4,194,304 B
// [+B*65536]               uint32 meta    [BATCH*8]             512 B
// [+B*8]                   uint8  mask    [BATCH*HW]        802,816 B
// total ~ 12.4 MB

__global__ void zero_kernel(uint32_t* p, int n) {
    int i = blockIdx.x * blockDim.x + threadIdx.x;
    int stride = gridDim.x * blockDim.x;
    for (; i < n; i += stride) p[i] = 0u;
}

// Energy per position, bit-exact vs numpy: sequential fp32 accumulation over c
// of fp32-rounded x*x (no FMA contraction), then correctly-rounded fp32 sqrt
// (via double sqrt; double-rounding is innocuous for sqrt since 53 >= 2*24+2).
__global__ void energy_kernel(const float* __restrict__ x,
                              uint32_t* __restrict__ ebits,
                              uint32_t* __restrict__ hist_hi) {
    int idx = blockIdx.x * blockDim.x + threadIdx.x;   // 0 .. BATCH*HW4-1
    int b = idx / HW4;
    int p = idx - b * HW4;
    const float4* xb = reinterpret_cast<const float4*>(x + (size_t)b * CH * HW) + p;
    float a0 = 0.f, a1 = 0.f, a2 = 0.f, a3 = 0.f;
    #pragma unroll 8
    for (int c = 0; c < CH; ++c) {
        float4 v = xb[(size_t)c * HW4];
        a0 = __fadd_rn(a0, __fmul_rn(v.x, v.x));
        a1 = __fadd_rn(a1, __fmul_rn(v.y, v.y));
        a2 = __fadd_rn(a2, __fmul_rn(v.z, v.z));
        a3 = __fadd_rn(a3, __fmul_rn(v.w, v.w));
    }
    uint4 bits;
    bits.x = __float_as_uint((float)sqrt((double)a0));
    bits.y = __float_as_uint((float)sqrt((double)a1));
    bits.z = __float_as_uint((float)sqrt((double)a2));
    bits.w = __float_as_uint((float)sqrt((double)a3));
    reinterpret_cast<uint4*>(ebits)[idx] = bits;   // ebits[idx*4 ..] == [b*HW + p*4 ..]
    uint32_t* h = hist_hi + (size_t)b * 65536;
    atomicAdd(&h[bits.x >> 16], 1u);
    atomicAdd(&h[bits.y >> 16], 1u);
    atomicAdd(&h[bits.z >> 16], 1u);
    atomicAdd(&h[bits.w >> 16], 1u);
}

// One block per batch: find the hi-16 bucket containing the k-th largest.
__global__ void scan_hi_kernel(const uint32_t* __restrict__ hist_hi,
                               uint32_t* __restrict__ meta) {
    int b = blockIdx.x;
    const uint32_t* h = hist_hi + (size_t)b * 65536;
    __shared__ uint32_t csum[256];
    int t = threadIdx.x;                      // 256 threads, 256 bins each
    uint32_t s = 0;
    for (int i = 0; i < 256; ++i) s += h[t * 256 + i];
    csum[t] = s;
    __syncthreads();
    if (t == 0) {
        uint32_t cum = 0; int ch = 255;
        for (; ch >= 0; --ch) {
            if (cum + csum[ch] >= KSEL) break;
            cum += csum[ch];
        }
        uint32_t cum2 = cum; uint32_t hi_bin = 0, greater = 0;
        for (int bin = ch * 256 + 255; bin >= ch * 256; --bin) {
            uint32_t cnt = h[bin];
            if (cum2 + cnt >= KSEL) { hi_bin = (uint32_t)bin; greater = cum2; break; }
            cum2 += cnt;
        }
        meta[b * 8 + 0] = hi_bin;
        meta[b * 8 + 1] = greater;   // count strictly above hi bucket
    }
}

__global__ void hist_lo_kernel(const uint32_t* __restrict__ ebits,
                               const uint32_t* __restrict__ meta,
                               uint32_t* __restrict__ hist_lo) {
    int idx = blockIdx.x * blockDim.x + threadIdx.x;   // BATCH*HW threads
    int b = idx / HW;
    uint32_t bits = ebits[idx];
    uint32_t hi = meta[b * 8 + 0];
    if ((bits >> 16) == hi)
        atomicAdd(&hist_lo[(size_t)b * 65536 + (bits & 0xFFFFu)], 1u);
}

// One block per batch: exact threshold bits, count-strictly-greater g, r = k-g.
__global__ void scan_lo_kernel(const uint32_t* __restrict__ hist_lo,
                               uint32_t* __restrict__ meta) {
    int b = blockIdx.x;
    const uint32_t* h = hist_lo + (size_t)b * 65536;
    __shared__ uint32_t csum[256];
    int t = threadIdx.x;
    uint32_t s = 0;
    for (int i = 0; i < 256; ++i) s += h[t * 256 + i];
    csum[t] = s;
    __syncthreads();
    if (t == 0) {
        uint32_t greater_hi = meta[b * 8 + 1];
        uint32_t target = KSEL - greater_hi;          // >= 1 by construction
        uint32_t cum = 0; int ch = 255;
        for (; ch >= 0; --ch) {
            if (cum + csum[ch] >= target) break;
            cum += csum[ch];
        }
        uint32_t cum2 = cum; uint32_t lo_bin = 0, greater_lo = 0;
        for (int bin = ch * 256 + 255; bin >= ch * 256; --bin) {
            uint32_t cnt = h[bin];
            if (cum2 + cnt >= target) { lo_bin = (uint32_t)bin; greater_lo = cum2; break; }
            cum2 += cnt;
        }
        uint32_t hi = meta[b * 8 + 0];
        uint32_t thr = (hi << 16) | lo_bin;
        uint32_t g = greater_hi + greater_lo;          // strictly greater than thr
        meta[b * 8 + 2] = thr;
        meta[b * 8 + 3] = g;
        meta[b * 8 + 4] = KSEL - g;                    // r ties to include (lowest idx)
    }
}

// One block per batch: ordered scan assigning tie ranks; write byte mask.
__global__ void mask_kernel(const uint32_t* __restrict__ ebits,
                            const uint32_t* __restrict__ meta,
                            uint8_t* __restrict__ mask) {
    int b = blockIdx.x;
    const uint32_t thr = meta[b * 8 + 2];
    const uint32_t r   = meta[b * 8 + 4];
    const uint32_t* eb = ebits + (size_t)b * HW;
    uint8_t* mb = mask + (size_t)b * HW;
    __shared__ uint32_t sc[1024];
    __shared__ uint32_t s_running;
    const int t = threadIdx.x;
    if (t == 0) s_running = 0;
    __syncthreads();
    for (int base = 0; base < HW; base += 1024) {
        int i = base + t;
        uint32_t bits = (i < HW) ? eb[i] : 0u;
        uint32_t pred = (i < HW && bits == thr) ? 1u : 0u;
        sc[t] = pred;
        __syncthreads();
        // Hillis-Steele inclusive scan over 1024
        for (int off = 1; off < 1024; off <<= 1) {
            uint32_t v = (t >= off) ? sc[t - off] : 0u;
            __syncthreads();
            sc[t] += v;
            __syncthreads();
        }
        uint32_t incl = sc[t];
        uint32_t excl = incl - pred;
        uint32_t running = s_running;   // value from previous chunk (stable since last sync)
        if (i < HW) {
            uint8_t m = 0;
            if (bits > thr) m = 1;
            else if (pred && (running + excl) < r) m = 1;
            mb[i] = m;
        }
        __syncthreads();
        if (t == 1023) s_running = running + incl;   // incl of t=1023 == chunk total
        __syncthreads();
    }
}

__global__ void apply_kernel(const float* __restrict__ x,
                             const uint8_t* __restrict__ mask,
                             float* __restrict__ out) {
    uint32_t idx = blockIdx.x * blockDim.x + threadIdx.x;   // element/4 index
    uint32_t e = idx * 4u;
    uint32_t b = e / (CH * HW);
    uint32_t rem = e - b * (CH * HW);
    uint32_t hw = rem % HW;
    float4 v = reinterpret_cast<const float4*>(x)[idx];
    uchar4 m = *reinterpret_cast<const uchar4*>(mask + (size_t)b * HW + hw);
    v.x = m.x ? v.x : 0.0f;
    v.y = m.y ? v.y : 0.0f;
    v.z = m.z ? v.z : 0.0f;
    v.w = m.w ? v.w : 0.0f;
    reinterpret_cast<float4*>(out)[idx] = v;
}

extern "C" void kernel_launch(void* const* d_in, const int* in_sizes, int n_in,
                              void* d_out, int out_size, void* d_ws, size_t ws_size,
                              hipStream_t stream) {
    const float* x = (const float*)d_in[0];
    float* out = (float*)d_out;

    uint32_t* ebits   = (uint32_t*)d_ws;
    uint32_t* hist_hi = ebits + (size_t)BATCH * HW;
    uint32_t* hist_lo = hist_hi + (size_t)BATCH * 65536;
    uint32_t* meta    = hist_lo + (size_t)BATCH * 65536;
    uint8_t*  mask    = (uint8_t*)(meta + BATCH * 8);

    // zero the histograms + meta (ws is poisoned 0xAA before every launch)
    int nzero = BATCH * 65536 * 2 + BATCH * 8;
    zero_kernel<<<2048, 1024, 0, stream>>>(hist_hi, nzero);

    // energy + hi-16 histogram: BATCH*HW4 = 200,704 threads
    energy_kernel<<<(BATCH * HW4) / 256, 256, 0, stream>>>(x, ebits, hist_hi);

    scan_hi_kernel<<<BATCH, 256, 0, stream>>>(hist_hi, meta);

    hist_lo_kernel<<<(BATCH * HW) / 256, 256, 0, stream>>>(ebits, meta, hist_lo);

    scan_lo_kernel<<<BATCH, 256, 0, stream>>>(hist_lo, meta);

    mask_kernel<<<BATCH, 1024, 0, stream>>>(ebits, meta, mask);

    // masked multiply: BATCH*CH*HW/4 = 19,267,584 threads
    apply_kernel<<<(BATCH * CH * HW / 4) / 256, 256, 0, stream>>>(x, mask, out);
}